// Round 5
// baseline (125.696 us; speedup 1.0000x reference)
//
#include <hip/hip_runtime.h>
#include <hip/hip_fp16.h>

#define C_COLS 8192

// ---------------------------------------------------------------------------
// Table kernel: z = ndtri((i+0.5)/16) in f64 (A&S seed + 3 Newton steps on
// Phi via erfc, ~2e-16), cast f32, normalized by max|z| with IEEE f32 divide,
// rounded through fp16 RNE.  (R2==R3 proved the fp16 table is insensitive to
// the normalize precision — table is not the failing component.)
// ---------------------------------------------------------------------------
__global__ void nf4_table_kernel(float* __restrict__ tbl_f32) {
    __shared__ float zf[16];
    const int i = threadIdx.x;
    if (i < 16) {
        double p  = (2.0 * i + 1.0) / 32.0;            // exact in binary
        double pl = (p < 0.5) ? p : 1.0 - p;
        double t  = sqrt(-2.0 * log(pl));
        double z  = t - (2.30753 + 0.27061 * t) / (1.0 + t * (0.99229 + 0.04481 * t));
        if (p < 0.5) z = -z;
        for (int it = 0; it < 3; ++it) {               // Newton on Phi(z)-p
            double Phi = 0.5 * erfc(-z * 0.7071067811865476);
            double phi = 0.3989422804014326779 * exp(-0.5 * z * z);
            z -= (Phi - p) / phi;
        }
        zf[i] = (float)z;
    }
    __syncthreads();
    if (i < 16) {
        float qmax = 0.0f;
        for (int j = 0; j < 16; ++j) qmax = fmaxf(qmax, fabsf(zf[j]));
        float qn = zf[i] / qmax;                       // IEEE f32 divide
        tbl_f32[i] = __half2float(__float2half(qn));   // fp16 RNE round-trip
    }
}

// ---------------------------------------------------------------------------
// Main kernel: one workgroup (256 thr = 4 waves) per row; wave w owns floats
// [w*2048, w*2048+2048); load k: lane holds float4 at elem 256k+4*lane; each
// 16-lane group holds one contiguous 64-elem quant-block.
//
// x_norm replicates XLA-CPU DEFAULT codegen (no fast-math, no contract) of
//     2.0*(xb - x_min)/(xmax - xmin + eps) - 1.0
// after the algebraic-simplifier broadcast-divisor hoist:
//     r  = round32(1/den)        (den broadcast (R,nb,1) -> hoisted recip)
//     p  = round32(2*(x-bm) * r) (one rounding; *2 exact)
//     xn = round32(p - 1.0f)     (separate sub, NO fma)
// Implemented as s2r = 2.0f/den (== 2*round(1/den) exactly, *2 commutes),
// p = (x-bm)*s2r, xn = p-1.0f, with fp contract OFF so nothing re-fuses.
// Argmin: 16-way f32 |xn-t| scan, strict '<' keeps first min (np/jnp argmin).
// ---------------------------------------------------------------------------
__global__ void nf4_main_kernel(const float* __restrict__ x,
                                float* __restrict__ out,
                                const float* __restrict__ tblg) {
#pragma clang fp contract(off)
    float tbl[16];
#pragma unroll
    for (int i = 0; i < 16; ++i) tbl[i] = tblg[i];

    const int row  = blockIdx.x;
    const int wave = threadIdx.x >> 6;
    const int lane = threadIdx.x & 63;
    const long base = (long)row * C_COLS + (long)wave * 2048;
    const float4* __restrict__ xin4 = reinterpret_cast<const float4*>(x + base);
    float4* __restrict__ out4       = reinterpret_cast<float4*>(out + base);

    __shared__ float smin[4], smax[4];

    float4 v[8];
    float bmin[8], bmax[8], srec[8];
    float tmin = 3.4e38f, tmax = -3.4e38f;

#pragma unroll
    for (int k = 0; k < 8; ++k) {
        v[k] = xin4[k * 64 + lane];                    // coalesced 1 KiB/wave
        float m = fminf(fminf(v[k].x, v[k].y), fminf(v[k].z, v[k].w));
        float M = fmaxf(fmaxf(v[k].x, v[k].y), fmaxf(v[k].z, v[k].w));
#pragma unroll
        for (int off = 1; off < 16; off <<= 1) {       // 16-lane group reduce
            m = fminf(m, __shfl_xor(m, off));
            M = fmaxf(M, __shfl_xor(M, off));
        }
        bmin[k] = m;
        bmax[k] = M;
        float sc = M - m;                              // exact
        tmin = fminf(tmin, sc);
        tmax = fmaxf(tmax, sc);
    }
    tmin = fminf(tmin, __shfl_xor(tmin, 16));
    tmin = fminf(tmin, __shfl_xor(tmin, 32));
    tmax = fmaxf(tmax, __shfl_xor(tmax, 16));
    tmax = fmaxf(tmax, __shfl_xor(tmax, 32));

    if (lane == 0) { smin[wave] = tmin; smax[wave] = tmax; }
    __syncthreads();
    const float s_min  = fminf(fminf(smin[0], smin[1]), fminf(smin[2], smin[3]));
    const float s_max  = fmaxf(fmaxf(smax[0], smax[1]), fmaxf(smax[2], smax[3]));
    const float srange = s_max - s_min;
    const float sden   = srange + 1e-8f;
    const float sqr    = 1.0f / sden;                  // broadcast recip hoist

#pragma unroll
    for (int k = 0; k < 8; ++k) {
        float sc = bmax[k] - bmin[k];
        // recip-mul form of (sc-s_min)/sden*255; off-by-one costs <=0.03
        float sq = rintf(((sc - s_min) * sqr) * 255.0f);   // RNE = np.round
        srec[k]  = s_min + sq / 255.0f * srange;
    }

#pragma unroll
    for (int k = 0; k < 8; ++k) {
        const float bm  = bmin[k];
        const float den = (bmax[k] - bm) + 1e-8f;
        const float s2r = 2.0f / den;                  // == 2*round(1/den) exactly
        const float sr  = srec[k];
        float xv[4] = { v[k].x, v[k].y, v[k].z, v[k].w };
        float wv[4];
#pragma unroll
        for (int c = 0; c < 4; ++c) {
            // XLA default: recip-mul, then SEPARATE subtract (no fma)
            float p  = (xv[c] - bm) * s2r;
            float xn = p - 1.0f;
            // full 16-way argmin, strict '<' keeps FIRST min (np.argmin)
            float best = fabsf(xn - tbl[0]);
            float tsel = tbl[0];
#pragma unroll
            for (int i = 1; i < 16; ++i) {
                float d = fabsf(xn - tbl[i]);
                if (d < best) { best = d; tsel = tbl[i]; }
            }
            wv[c] = (tsel + 1.0f) * 0.5f * sr + bm;    // mul+add, contract off
        }
        float4 r; r.x = wv[0]; r.y = wv[1]; r.z = wv[2]; r.w = wv[3];
        out4[k * 64 + lane] = r;
    }
}

extern "C" void kernel_launch(void* const* d_in, const int* in_sizes, int n_in,
                              void* d_out, int out_size, void* d_ws, size_t ws_size,
                              hipStream_t stream) {
    const float* x = (const float*)d_in[0];
    float* out     = (float*)d_out;
    float* tbl     = (float*)d_ws;                     // 16 f32, rewritten per launch
    const int rows = in_sizes[0] / C_COLS;

    nf4_table_kernel<<<1, 64, 0, stream>>>(tbl);
    nf4_main_kernel<<<rows, 256, 0, stream>>>(x, out, tbl);
}